// Round 1
// baseline (461.549 us; speedup 1.0000x reference)
//
#include <hip/hip_runtime.h>

// ModulatedConv2d: B=16, C=512->512, 3x3 SAME, per-sample demodulated weights.
// Plan: prepass (style GEMM, demod norms, bf16 weight materialization [b][t][o][i],
// channels-last zero-padded bf16 input) + MFMA implicit-GEMM conv
// (9 shifted tap-GEMMs accumulated in AGPRs), m97 128x128-tile structure.

typedef __bf16 bf16x8 __attribute__((ext_vector_type(8)));
typedef float f32x4 __attribute__((ext_vector_type(4)));

__device__ __forceinline__ void async16(const void* g, void* s) {
  __builtin_amdgcn_global_load_lds((const __attribute__((address_space(1))) void*)g,
                                   (__attribute__((address_space(3))) void*)s, 16, 0, 0);
}

// style[b][i] = dot(w_embs[b,:], style_W[i,:]) + style_b[i] + 1
__global__ __launch_bounds__(256) void k_style(const float* __restrict__ we,
                                               const float* __restrict__ sW,
                                               const float* __restrict__ sb,
                                               float* __restrict__ style) {
  int lane = threadIdx.x & 63, wid = threadIdx.x >> 6;
  int b = blockIdx.x >> 7;
  int i = ((blockIdx.x & 127) << 2) + wid;
  const float* wer = we + b * 512;
  const float* swr = sW + i * 512;
  float acc = 0.f;
  for (int d = lane; d < 512; d += 64) acc += wer[d] * swr[d];
#pragma unroll
  for (int off = 32; off; off >>= 1) acc += __shfl_xor(acc, off);
  if (lane == 0) style[b * 512 + i] = acc + sb[i] + 1.0f;
}

// wsq[o][i] = sum_k cw[o][i][k]^2
__global__ __launch_bounds__(256) void k_wsq(const float* __restrict__ cw,
                                             float* __restrict__ wsq) {
  int t = blockIdx.x * 256 + threadIdx.x;  // o*512+i
  const float* p = cw + (long)t * 9;
  float s = 0.f;
#pragma unroll
  for (int k = 0; k < 9; ++k) s += p[k] * p[k];
  wsq[t] = s;
}

// rnorm[b][o] = rsqrt(sum_i style[b,i]^2 * wsq[o,i])   (exact f32 demod)
__global__ __launch_bounds__(256) void k_rnorm(const float* __restrict__ style,
                                               const float* __restrict__ wsq,
                                               float* __restrict__ rnorm) {
  int lane = threadIdx.x & 63, wid = threadIdx.x >> 6;
  int idx = blockIdx.x * 4 + wid;  // b*512 + o
  int b = idx >> 9, o = idx & 511;
  float acc = 0.f;
  for (int i = lane; i < 512; i += 64) {
    float s = style[(b << 9) + i];
    acc += s * s * wsq[(o << 9) + i];
  }
#pragma unroll
  for (int off = 32; off; off >>= 1) acc += __shfl_xor(acc, off);
  if (lane == 0) rnorm[idx] = rsqrtf(acc);
}

// wt[b][t][o][i] = bf16( cw[o][i][t] * style[b][i] * rnorm[b][o] )
__global__ __launch_bounds__(256) void k_wt(const float* __restrict__ cw,
                                            const float* __restrict__ style,
                                            const float* __restrict__ rnorm,
                                            __bf16* __restrict__ wt) {
  int t = blockIdx.x * 256 + threadIdx.x;  // b*262144 + o*512 + i
  int b = t >> 18;
  int oi = t & 262143;
  int o = oi >> 9, i = oi & 511;
  float sc = style[(b << 9) + i] * rnorm[(b << 9) + o];
  const float* p = cw + (long)oi * 9;
#pragma unroll
  for (int k = 0; k < 9; ++k)
    wt[((long)(b * 9 + k) << 18) + ((long)o << 9) + i] = (__bf16)(p[k] * sc);
}

// xpad[b][r][c][i] (r,c in [0,66)) = bf16(imgs[b][i][r-1][c-1]), zero on border.
// Channels-last so conv staging is linear & global_load_lds-able.
__global__ __launch_bounds__(256) void k_xpad(const float* __restrict__ imgs,
                                              __bf16* __restrict__ xpad) {
  int t = blockIdx.x * 256 + threadIdx.x;  // b*4356 + r*66 + c
  if (t >= 16 * 4356) return;
  int b = t / 4356;
  int rc = t - b * 4356;
  int r = rc / 66, c = rc - (rc / 66) * 66;
  __bf16* dst = xpad + (long)t * 512;
  if (r == 0 || r == 65 || c == 0 || c == 65) {
    const f32x4 z = {0.f, 0.f, 0.f, 0.f};
#pragma unroll 4
    for (int j = 0; j < 64; ++j) *(f32x4*)(dst + j * 8) = z;
  } else {
    const float* src = imgs + ((long)b << 21) + ((r - 1) << 6) + (c - 1);
    for (int j = 0; j < 64; ++j) {  // lane = c -> coalesced f32 reads per chan
      bf16x8 v;
#pragma unroll
      for (int q = 0; q < 8; ++q) v[q] = (__bf16)src[(long)(j * 8 + q) << 12];
      *(bf16x8*)(dst + j * 8) = v;
    }
  }
}

// Conv: block = 128 out-chans x 128 px (4h x 32w), 4 waves (2x2 of 64x64),
// K staged 64 chans/iter, 9 taps inner, mfma 16x16x32 bf16.
__global__ __launch_bounds__(256, 3) void k_conv(const __bf16* __restrict__ xpad,
                                                 const __bf16* __restrict__ wt,
                                                 const float* __restrict__ bias,
                                                 float* __restrict__ out) {
  __shared__ __attribute__((aligned(16))) __bf16 sX[224 * 64];  // 6x34=204 px used
  __shared__ __attribute__((aligned(16))) __bf16 sA[128 * 64];

  const int tid = threadIdx.x;
  const int lane = tid & 63;
  const int wid = tid >> 6;
  const int wr = wid >> 1, wc = wid & 1;
  const int l15 = lane & 15, lq = lane >> 4;

  const int bid = blockIdx.x;
  const int b = bid >> 7;          // 128 blocks / batch
  const int r7 = bid & 127;
  const int o0 = (r7 >> 5) << 7;   // 4 o-tiles of 128
  const int st = r7 & 31;          // 32 spatial tiles
  const int h0 = (st >> 1) << 2;   // 16 h-tiles * 4 rows
  const int w0 = (st & 1) << 5;    // 2 w-tiles * 32 cols

  // X staging: 1792 16B slots (224 px * 8 chunks); slot s -> px p=s>>3, chunk j=s&7.
  const __bf16* xg[7];
#pragma unroll
  for (int it = 0; it < 7; ++it) {
    int s = it * 256 + tid;
    int p = s >> 3, j = s & 7;
    int pp = (p < 204) ? p : 0;  // pad slots read dummy, never consumed
    int lr = pp / 34, lc = pp - lr * 34;
    xg[it] = xpad + ((long)((b * 66 + h0 + lr) * 66) + (w0 + lc)) * 512 + j * 8;
  }
  // A staging: 1024 slots; slot s -> row o=s>>3, chunk j=s&7.
  int aoff[4];
#pragma unroll
  for (int it = 0; it < 4; ++it) {
    int s = it * 256 + tid;
    aoff[it] = ((o0 + (s >> 3)) << 9) + ((s & 7) << 3);
  }
  const __bf16* wtb = wt + (long)b * (9 * 512 * 512);

  f32x4 acc[4][4];
  const f32x4 zero4 = {0.f, 0.f, 0.f, 0.f};
#pragma unroll
  for (int m = 0; m < 4; ++m)
#pragma unroll
    for (int n = 0; n < 4; ++n) acc[m][n] = zero4;

  int prn[4], pcn[4];
#pragma unroll
  for (int n = 0; n < 4; ++n) {
    int nn = (wc << 6) + (n << 4) + l15;
    prn[n] = nn >> 5;
    pcn[n] = nn & 31;
  }
  const int kbq = lq << 3;
  const int arow = ((wr << 6) + l15) << 6;

  for (int ic = 0; ic < 512; ic += 64) {
#pragma unroll
    for (int t = 0; t < 9; ++t) {
      __syncthreads();  // prior MFMA reads of sA/sX complete
      if (t == 0) {
#pragma unroll
        for (int it = 0; it < 7; ++it)
          async16(xg[it] + ic, (char*)sX + (it * 256 + (wid << 6)) * 16);
      }
      {
        const __bf16* wa = wtb + t * (512 * 512) + ic;
#pragma unroll
        for (int it = 0; it < 4; ++it)
          async16(wa + aoff[it], (char*)sA + (it * 256 + (wid << 6)) * 16);
      }
      __syncthreads();  // compiler drains vmcnt before s_barrier -> LDS ready
      const int ky = t / 3, kx = t - (t / 3) * 3;
#pragma unroll
      for (int kk = 0; kk < 2; ++kk) {
        const int kb = (kk << 5) + kbq;
        bf16x8 af[4], bf[4];
#pragma unroll
        for (int m = 0; m < 4; ++m)
          af[m] = *(const bf16x8*)&sA[arow + (m << 10) + kb];
#pragma unroll
        for (int n = 0; n < 4; ++n) {
          int p = (prn[n] + ky) * 34 + pcn[n] + kx;
          bf[n] = *(const bf16x8*)&sX[(p << 6) + kb];
        }
#pragma unroll
        for (int m = 0; m < 4; ++m)
#pragma unroll
          for (int n = 0; n < 4; ++n)
            acc[m][n] = __builtin_amdgcn_mfma_f32_16x16x32_bf16(af[m], bf[n],
                                                                acc[m][n], 0, 0, 0);
      }
    }
  }

  // Epilogue: C/D layout col=lane&15 (pixel), row=(lane>>4)*4+q (out chan).
  float* outb = out + ((long)b << 21);
#pragma unroll
  for (int m = 0; m < 4; ++m) {
    int ob = o0 + (wr << 6) + (m << 4) + (lq << 2);
#pragma unroll
    for (int n = 0; n < 4; ++n) {
      int h = h0 + prn[n], w = w0 + pcn[n];
#pragma unroll
      for (int q = 0; q < 4; ++q) {
        int o = ob + q;
        outb[((long)o << 12) + (h << 6) + w] = acc[m][n][q] + bias[o];
      }
    }
  }
}

extern "C" void kernel_launch(void* const* d_in, const int* in_sizes, int n_in,
                              void* d_out, int out_size, void* d_ws, size_t ws_size,
                              hipStream_t stream) {
  const float* imgs = (const float*)d_in[0];
  const float* w_embs = (const float*)d_in[1];
  const float* cw = (const float*)d_in[2];
  const float* bias = (const float*)d_in[3];
  const float* style_W = (const float*)d_in[4];
  const float* style_b = (const float*)d_in[5];
  float* out = (float*)d_out;

  char* ws = (char*)d_ws;
  float* style = (float*)(ws);                          // 32 KB
  float* rnorm = (float*)(ws + (32 << 10));             // 32 KB
  float* wsq = (float*)(ws + (64 << 10));               // 1 MB
  __bf16* wt = (__bf16*)(ws + (64 << 10) + (1 << 20));  // 75,497,472 B
  __bf16* xpad = (__bf16*)(ws + (64 << 10) + (1 << 20) + 75497472);  // 71,368,704 B
  size_t need = (size_t)(64 << 10) + (1 << 20) + 75497472ull + 71368704ull;
  if (ws_size < need) return;  // leaves d_out poisoned -> visible failure mode

  k_style<<<2048, 256, 0, stream>>>(w_embs, style_W, style_b, style);
  k_wsq<<<1024, 256, 0, stream>>>(cw, wsq);
  k_rnorm<<<2048, 256, 0, stream>>>(style, wsq, rnorm);
  k_wt<<<16384, 256, 0, stream>>>(cw, style, rnorm, wt);
  k_xpad<<<273, 256, 0, stream>>>(imgs, xpad);
  k_conv<<<2048, 256, 0, stream>>>(xpad, wt, bias, out);
}

// Round 2
// 393.910 us; speedup vs baseline: 1.1717x; 1.1717x over previous
//
#include <hip/hip_runtime.h>

// ModulatedConv2d: B=16, C=512->512, 3x3 SAME, per-sample demodulated weights.
// Prepass (style GEMM, demod norms, bf16 weights [b][t][o][i], channels-last
// padded bf16 input) + MFMA implicit-GEMM conv (9 shifted tap-GEMMs).
// R1: T2 XOR chunk-swizzle on sA/sX (16-way bank conflict -> 2-way free).
//     Swizzle applied as pre-swizzled GLOBAL source (LDS dest of
//     global_load_lds must stay linear) + same XOR on ds_read address.

typedef __bf16 bf16x8 __attribute__((ext_vector_type(8)));
typedef float f32x4 __attribute__((ext_vector_type(4)));

__device__ __forceinline__ void async16(const void* g, void* s) {
  __builtin_amdgcn_global_load_lds((const __attribute__((address_space(1))) void*)g,
                                   (__attribute__((address_space(3))) void*)s, 16, 0, 0);
}

// style[b][i] = dot(w_embs[b,:], style_W[i,:]) + style_b[i] + 1
__global__ __launch_bounds__(256) void k_style(const float* __restrict__ we,
                                               const float* __restrict__ sW,
                                               const float* __restrict__ sb,
                                               float* __restrict__ style) {
  int lane = threadIdx.x & 63, wid = threadIdx.x >> 6;
  int b = blockIdx.x >> 7;
  int i = ((blockIdx.x & 127) << 2) + wid;
  const float* wer = we + b * 512;
  const float* swr = sW + i * 512;
  float acc = 0.f;
  for (int d = lane; d < 512; d += 64) acc += wer[d] * swr[d];
#pragma unroll
  for (int off = 32; off; off >>= 1) acc += __shfl_xor(acc, off);
  if (lane == 0) style[b * 512 + i] = acc + sb[i] + 1.0f;
}

// wsq[o][i] = sum_k cw[o][i][k]^2
__global__ __launch_bounds__(256) void k_wsq(const float* __restrict__ cw,
                                             float* __restrict__ wsq) {
  int t = blockIdx.x * 256 + threadIdx.x;  // o*512+i
  const float* p = cw + (long)t * 9;
  float s = 0.f;
#pragma unroll
  for (int k = 0; k < 9; ++k) s += p[k] * p[k];
  wsq[t] = s;
}

// rnorm[b][o] = rsqrt(sum_i style[b,i]^2 * wsq[o,i])   (exact f32 demod)
__global__ __launch_bounds__(256) void k_rnorm(const float* __restrict__ style,
                                               const float* __restrict__ wsq,
                                               float* __restrict__ rnorm) {
  int lane = threadIdx.x & 63, wid = threadIdx.x >> 6;
  int idx = blockIdx.x * 4 + wid;  // b*512 + o
  int b = idx >> 9, o = idx & 511;
  float acc = 0.f;
  for (int i = lane; i < 512; i += 64) {
    float s = style[(b << 9) + i];
    acc += s * s * wsq[(o << 9) + i];
  }
#pragma unroll
  for (int off = 32; off; off >>= 1) acc += __shfl_xor(acc, off);
  if (lane == 0) rnorm[idx] = rsqrtf(acc);
}

// wt[b][t][o][i] = bf16( cw[o][i][t] * style[b][i] * rnorm[b][o] )
__global__ __launch_bounds__(256) void k_wt(const float* __restrict__ cw,
                                            const float* __restrict__ style,
                                            const float* __restrict__ rnorm,
                                            __bf16* __restrict__ wt) {
  int t = blockIdx.x * 256 + threadIdx.x;  // b*262144 + o*512 + i
  int b = t >> 18;
  int oi = t & 262143;
  int o = oi >> 9, i = oi & 511;
  float sc = style[(b << 9) + i] * rnorm[(b << 9) + o];
  const float* p = cw + (long)oi * 9;
#pragma unroll
  for (int k = 0; k < 9; ++k)
    wt[((long)(b * 9 + k) << 18) + ((long)o << 9) + i] = (__bf16)(p[k] * sc);
}

// xpad[b][r][c][i] (r,c in [0,66)) = bf16(imgs[b][i][r-1][c-1]), zero on border.
__global__ __launch_bounds__(256) void k_xpad(const float* __restrict__ imgs,
                                              __bf16* __restrict__ xpad) {
  int t = blockIdx.x * 256 + threadIdx.x;  // b*4356 + r*66 + c
  if (t >= 16 * 4356) return;
  int b = t / 4356;
  int rc = t - b * 4356;
  int r = rc / 66, c = rc - (rc / 66) * 66;
  __bf16* dst = xpad + (long)t * 512;
  if (r == 0 || r == 65 || c == 0 || c == 65) {
    const f32x4 z = {0.f, 0.f, 0.f, 0.f};
#pragma unroll 4
    for (int j = 0; j < 64; ++j) *(f32x4*)(dst + j * 8) = z;
  } else {
    const float* src = imgs + ((long)b << 21) + ((r - 1) << 6) + (c - 1);
    for (int j = 0; j < 64; ++j) {
      bf16x8 v;
#pragma unroll
      for (int q = 0; q < 8; ++q) v[q] = (__bf16)src[(long)(j * 8 + q) << 12];
      *(bf16x8*)(dst + j * 8) = v;
    }
  }
}

// Conv: block = 128 out-chans x 128 px (4h x 32w), 4 waves (2x2 of 64x64),
// K staged 64 chans/iter, 9 taps inner, mfma 16x16x32 bf16.
// LDS rows are 128B (8 chunks of 16B); chunk swizzle j' = j ^ (row&7).
__global__ __launch_bounds__(256, 3) void k_conv(const __bf16* __restrict__ xpad,
                                                 const __bf16* __restrict__ wt,
                                                 const float* __restrict__ bias,
                                                 float* __restrict__ out) {
  __shared__ __attribute__((aligned(16))) __bf16 sX[224 * 64];  // 6x34=204 px used
  __shared__ __attribute__((aligned(16))) __bf16 sA[128 * 64];

  const int tid = threadIdx.x;
  const int lane = tid & 63;
  const int wid = tid >> 6;
  const int wr = wid >> 1, wc = wid & 1;
  const int l15 = lane & 15, lq = lane >> 4, l7 = lane & 7;

  const int bid = blockIdx.x;
  const int b = bid >> 7;          // 128 blocks / batch
  const int r7 = bid & 127;
  const int o0 = (r7 >> 5) << 7;   // 4 o-tiles of 128
  const int st = r7 & 31;          // 32 spatial tiles
  const int h0 = (st >> 1) << 2;   // 16 h-tiles * 4 rows
  const int w0 = (st & 1) << 5;    // 2 w-tiles * 32 cols

  // X staging: 1792 16B slots; slot s -> px p=s>>3, holds chunk j=(s&7)^(p&7).
  const __bf16* xg[7];
#pragma unroll
  for (int it = 0; it < 7; ++it) {
    int s = it * 256 + tid;
    int p = s >> 3;
    int pp = (p < 204) ? p : 0;  // pad slots read dummy, never consumed
    int j = (s & 7) ^ (pp & 7);
    int lr = pp / 34, lc = pp - lr * 34;
    xg[it] = xpad + ((long)((b * 66 + h0 + lr) * 66) + (w0 + lc)) * 512 + j * 8;
  }
  // A staging: 1024 slots; slot s -> row o=s>>3, holds chunk j=(s&7)^(row&7).
  int aoff[4];
#pragma unroll
  for (int it = 0; it < 4; ++it) {
    int s = it * 256 + tid;
    int row = s >> 3;
    int j = (s & 7) ^ (row & 7);
    aoff[it] = ((o0 + row) << 9) + (j << 3);
  }
  const __bf16* wtb = wt + (long)b * (9 * 512 * 512);

  f32x4 acc[4][4];
  const f32x4 zero4 = {0.f, 0.f, 0.f, 0.f};
#pragma unroll
  for (int m = 0; m < 4; ++m)
#pragma unroll
    for (int n = 0; n < 4; ++n) acc[m][n] = zero4;

  int prn[4], pcn[4];
#pragma unroll
  for (int n = 0; n < 4; ++n) {
    int nn = (wc << 6) + (n << 4) + l15;
    prn[n] = nn >> 5;
    pcn[n] = nn & 31;
  }
  const int arow = ((wr << 6) + l15) << 6;  // A row base (elements)

  for (int ic = 0; ic < 512; ic += 64) {
#pragma unroll
    for (int t = 0; t < 9; ++t) {
      __syncthreads();  // prior MFMA reads of sA/sX complete
      if (t == 0) {
#pragma unroll
        for (int it = 0; it < 7; ++it)
          async16(xg[it] + ic, (char*)sX + (it * 256 + (wid << 6)) * 16);
      }
      {
        const __bf16* wa = wtb + t * (512 * 512) + ic;
#pragma unroll
        for (int it = 0; it < 4; ++it)
          async16(wa + aoff[it], (char*)sA + (it * 256 + (wid << 6)) * 16);
      }
      __syncthreads();  // vmcnt drained before barrier -> LDS ready
      const int ky = t / 3, kx = t - (t / 3) * 3;
#pragma unroll
      for (int kk = 0; kk < 2; ++kk) {
        const int jb = lq + (kk << 2);   // unswizzled chunk index for this lane
        const int jA = (jb ^ l7) << 3;   // A: row&7 == l7
        bf16x8 af[4], bf[4];
#pragma unroll
        for (int m = 0; m < 4; ++m)
          af[m] = *(const bf16x8*)&sA[arow + (m << 10) + jA];
#pragma unroll
        for (int n = 0; n < 4; ++n) {
          int p = (prn[n] + ky) * 34 + pcn[n] + kx;
          bf[n] = *(const bf16x8*)&sX[(p << 6) + ((jb ^ (p & 7)) << 3)];
        }
#pragma unroll
        for (int m = 0; m < 4; ++m)
#pragma unroll
          for (int n = 0; n < 4; ++n)
            acc[m][n] = __builtin_amdgcn_mfma_f32_16x16x32_bf16(af[m], bf[n],
                                                                acc[m][n], 0, 0, 0);
      }
    }
  }

  // Epilogue: C/D layout col=lane&15 (pixel), row=(lane>>4)*4+q (out chan).
  float* outb = out + ((long)b << 21);
#pragma unroll
  for (int m = 0; m < 4; ++m) {
    int ob = o0 + (wr << 6) + (m << 4) + (lq << 2);
#pragma unroll
    for (int n = 0; n < 4; ++n) {
      int h = h0 + prn[n], w = w0 + pcn[n];
#pragma unroll
      for (int q = 0; q < 4; ++q) {
        int o = ob + q;
        outb[((long)o << 12) + (h << 6) + w] = acc[m][n][q] + bias[o];
      }
    }
  }
}

extern "C" void kernel_launch(void* const* d_in, const int* in_sizes, int n_in,
                              void* d_out, int out_size, void* d_ws, size_t ws_size,
                              hipStream_t stream) {
  const float* imgs = (const float*)d_in[0];
  const float* w_embs = (const float*)d_in[1];
  const float* cw = (const float*)d_in[2];
  const float* bias = (const float*)d_in[3];
  const float* style_W = (const float*)d_in[4];
  const float* style_b = (const float*)d_in[5];
  float* out = (float*)d_out;

  char* ws = (char*)d_ws;
  float* style = (float*)(ws);                          // 32 KB
  float* rnorm = (float*)(ws + (32 << 10));             // 32 KB
  float* wsq = (float*)(ws + (64 << 10));               // 1 MB
  __bf16* wt = (__bf16*)(ws + (64 << 10) + (1 << 20));  // 75,497,472 B
  __bf16* xpad = (__bf16*)(ws + (64 << 10) + (1 << 20) + 75497472);  // 71,368,704 B
  size_t need = (size_t)(64 << 10) + (1 << 20) + 75497472ull + 71368704ull;
  if (ws_size < need) return;  // leaves d_out poisoned -> visible failure mode

  k_style<<<2048, 256, 0, stream>>>(w_embs, style_W, style_b, style);
  k_wsq<<<1024, 256, 0, stream>>>(cw, wsq);
  k_rnorm<<<2048, 256, 0, stream>>>(style, wsq, rnorm);
  k_wt<<<16384, 256, 0, stream>>>(cw, style, rnorm, wt);
  k_xpad<<<273, 256, 0, stream>>>(imgs, xpad);
  k_conv<<<2048, 256, 0, stream>>>(xpad, wt, bias, out);
}